// Round 1
// baseline (3673.666 us; speedup 1.0000x reference)
//
#include <hip/hip_runtime.h>
#include <math.h>

#define N 4096
#define STEPS 16384
#define CHUNK 16
#define NCHUNK (STEPS / CHUNK)
#define MBLK 1024

// ---- thresholds: thr[t] = atanh(2*u[t]-1) in double (r computed in fp32 like ref) ----
__global__ __launch_bounds__(256) void thr_kernel(const float* __restrict__ u,
                                                  double* __restrict__ thr) {
  int t = blockIdx.x * 256 + threadIdx.x;
  if (t < STEPS) {
    float r = 2.0f * u[t] - 1.0f;          // exact same fp32 rounding as reference
    double rd = (double)r;
    thr[t] = 0.5 * log((1.0 + rd) / (1.0 - rd));   // r=-1 -> -inf (tie->+1 matches ref)
  }
}

// ---- initial field: I0[row] = sum_k J[row,k]*m0[k] + h[row], fp64 accumulate ----
__global__ __launch_bounds__(256) void init_field_kernel(const float* __restrict__ J,
                                                         const float* __restrict__ h,
                                                         const float* __restrict__ m0,
                                                         double* __restrict__ I) {
  __shared__ double red[256];
  int row = blockIdx.x;
  const float4* Jr = (const float4*)(J + (size_t)row * N);
  const float4* mv = (const float4*)m0;
  double acc = 0.0;
  for (int q = threadIdx.x; q < N / 4; q += 256) {
    float4 a = Jr[q];
    float4 b = mv[q];
    // m0 = +/-1 exactly -> products exact in fp32, summed in fp64
    acc += (double)(a.x * b.x) + (double)(a.y * b.y) +
           (double)(a.z * b.z) + (double)(a.w * b.w);
  }
  red[threadIdx.x] = acc;
  __syncthreads();
  for (int s = 128; s > 0; s >>= 1) {
    if (threadIdx.x < s) red[threadIdx.x] += red[threadIdx.x + s];
    __syncthreads();
  }
  if (threadIdx.x == 0) I[row] = red[0] + (double)h[row];
}

// ---- sequential chunk-resolved Glauber chain: 1 workgroup, 1024 threads ----
// Thread tid owns field elements 4*tid..4*tid+3 as fp64 registers.
// Per chunk of 16 steps: wave 0 resolves decisions serially via the 16x16
// coupling matrix S (prefetched one chunk ahead); then all waves apply the
// rank-F update with row loads only for flipped steps (uniform branches).
__global__ __launch_bounds__(MBLK) void pbit_kernel(const float* __restrict__ J,
                                                    const float* __restrict__ m0,
                                                    const int* __restrict__ idx,
                                                    const double* __restrict__ thr,
                                                    const double* __restrict__ I0,
                                                    float* __restrict__ out) {
  __shared__ __align__(16) float m_lds[N];
  __shared__ __align__(16) float S_lds[CHUNK * CHUNK];
  __shared__ double Ibase_lds[CHUNK];
  __shared__ float delta_lds[CHUNK];

  const int tid = threadIdx.x;

  // master field (fp64) for owned elements
  double i0, i1, i2, i3;
  {
    const double* ip = I0 + 4 * tid;
    i0 = ip[0]; i1 = ip[1]; i2 = ip[2]; i3 = ip[3];
  }
  ((float4*)m_lds)[tid] = ((const float4*)m0)[tid];
  __syncthreads();

  const int t16 = tid & 15;       // step slot within chunk (resolve duplication ok)
  const int gt = tid >> 2;        // S-gather row (valid for tid<64: 0..15)
  const int gq = (tid & 3) * 4;   // S-gather col group
  int myidx = 0, nidx = 0;
  double mythr = 0.0, nthr = 0.0;
  float mym = 0.0f;
  int grow = 0, gc0 = 0, gc1 = 0, gc2 = 0, gc3 = 0;

  if (tid < 64) {
    myidx = idx[t16];
    mythr = thr[t16];
    nidx = idx[CHUNK + t16];
    nthr = thr[CHUNK + t16];
    grow = idx[CHUNK + gt];
    gc0 = idx[CHUNK + gq + 0]; gc1 = idx[CHUNK + gq + 1];
    gc2 = idx[CHUNK + gq + 2]; gc3 = idx[CHUNK + gq + 3];
    // synchronous S gather for chunk 0
    int r0 = idx[gt];
    int c0 = idx[gq + 0], c1 = idx[gq + 1], c2 = idx[gq + 2], c3 = idx[gq + 3];
    const float* Jr = J + (size_t)r0 * N;
    S_lds[gt * CHUNK + gq + 0] = Jr[c0];
    S_lds[gt * CHUNK + gq + 1] = Jr[c1];
    S_lds[gt * CHUNK + gq + 2] = Jr[c2];
    S_lds[gt * CHUNK + gq + 3] = Jr[c3];
    mym = m_lds[myidx];
  }
  // publish base fields for chunk 0
#pragma unroll
  for (int t = 0; t < CHUNK; ++t) {
    int nt = idx[t];
    if (tid == (nt >> 2)) {
      int comp = nt & 3;
      double v = (comp == 0) ? i0 : (comp == 1) ? i1 : (comp == 2) ? i2 : i3;
      Ibase_lds[t] = v;
    }
  }
  __syncthreads();

  for (int c = 0; c < NCHUNK; ++c) {
    const int base = c * CHUNK;

    // ---------------- P1: wave 0 resolves the 16 decisions ----------------
    if (tid < 64) {
      // 1) issue S gather for chunk c+1 (addresses already in regs, no wait)
      const float* Jg = J + (size_t)grow * N;
      float g0 = Jg[gc0], g1 = Jg[gc1], g2 = Jg[gc2], g3 = Jg[gc3];
      // 2) issue idx/thr loads for chunk c+2 (consumed next iteration)
      int base2 = base + 2 * CHUNK;
      if (base2 >= STEPS) base2 = 0;   // clamp: values unused on final chunks
      int n2idx = idx[base2 + t16];
      double n2thr = thr[base2 + t16];
      int g2row = idx[base2 + gt];
      int g2c0 = idx[base2 + gq + 0], g2c1 = idx[base2 + gq + 1];
      int g2c2 = idx[base2 + gq + 2], g2c3 = idx[base2 + gq + 3];
      // 3) read this chunk's S row + base field
      float4 s0 = ((const float4*)S_lds)[t16 * 4 + 0];
      float4 s1 = ((const float4*)S_lds)[t16 * 4 + 1];
      float4 s2 = ((const float4*)S_lds)[t16 * 4 + 2];
      float4 s3 = ((const float4*)S_lds)[t16 * 4 + 3];
      double Ival = Ibase_lds[t16];
      float mcur = mym;
      float Srow[CHUNK] = {s0.x, s0.y, s0.z, s0.w, s1.x, s1.y, s1.z, s1.w,
                           s2.x, s2.y, s2.z, s2.w, s3.x, s3.y, s3.z, s3.w};
      float mydelta = 0.0f, mys = 0.0f;
      bool lastocc = true;
      // 4) serial resolve: lane t decides step t; broadcasts via readlane
#pragma unroll
      for (int tt = 0; tt < CHUNK; ++tt) {
        float s = (Ival >= mythr) ? 1.0f : -1.0f;   // I >= atanh(r)  <=>  tanh(I) >= r
        float dl = s - mcur;
        float dl_bc = __int_as_float(__builtin_amdgcn_readlane(__float_as_int(dl), tt));
        float s_bc = __int_as_float(__builtin_amdgcn_readlane(__float_as_int(s), tt));
        int i_bc = __builtin_amdgcn_readlane(myidx, tt);
        if (t16 == tt) { mydelta = dl; mys = s; }
        Ival += (double)(Srow[tt] * dl_bc);          // product exact: dl in {-2,0,2}
        if (myidx == i_bc) {                          // in-chunk duplicate index
          if (tt > t16) lastocc = false;
          mcur = s_bc;
        }
      }
      // 5) publish decisions + m updates (last occurrence wins)
      if (tid < CHUNK) {
        delta_lds[t16] = mydelta;
        if (lastocc) m_lds[myidx] = mys;
      }
      // 6) stage S for chunk c+1 (waits the gather issued in step 1)
      S_lds[gt * CHUNK + gq + 0] = g0;
      S_lds[gt * CHUNK + gq + 1] = g1;
      S_lds[gt * CHUNK + gq + 2] = g2;
      S_lds[gt * CHUNK + gq + 3] = g3;
      // 7) m gather for chunk c+1 (after this chunk's m writes; same wave)
      mym = m_lds[nidx];
      // 8) shift pipeline registers
      myidx = nidx; mythr = nthr;
      nidx = n2idx; nthr = n2thr;
      grow = g2row; gc0 = g2c0; gc1 = g2c1; gc2 = g2c2; gc3 = g2c3;
    }
    __syncthreads();

    // ---------------- P2: all threads apply rank-F update ----------------
    {
      float a0 = 0.f, a1 = 0.f, a2 = 0.f, a3 = 0.f;
      const float* Jb = J + 4 * tid;
#pragma unroll
      for (int g = 0; g < 2; ++g) {
        float4 rv[8];
        int db[8];
        float dv[8];
#pragma unroll
        for (int r = 0; r < 8; ++r) {
          int t = g * 8 + r;
          db[r] = __builtin_amdgcn_readfirstlane(__float_as_int(delta_lds[t]));
          dv[r] = __int_as_float(db[r]);
          if (db[r] != 0) {                 // uniform branch: row load only on flip
            int rowi = idx[base + t];
            rv[r] = *(const float4*)(Jb + (size_t)rowi * N);
          }
        }
#pragma unroll
        for (int r = 0; r < 8; ++r) {
          if (db[r] != 0) {
            a0 += rv[r].x * dv[r]; a1 += rv[r].y * dv[r];
            a2 += rv[r].z * dv[r]; a3 += rv[r].w * dv[r];
          }
        }
      }
      // chunk-local exact fp32 partials -> fp64 master (kills drift)
      i0 += (double)a0; i1 += (double)a1; i2 += (double)a2; i3 += (double)a3;
      // publish base fields for next chunk
      int nbase = base + CHUNK;
      if (nbase >= STEPS) nbase = 0;        // clamped garbage on last chunk, unused
#pragma unroll
      for (int t = 0; t < CHUNK; ++t) {
        int nt = idx[nbase + t];
        if (tid == (nt >> 2)) {
          int comp = nt & 3;
          double v = (comp == 0) ? i0 : (comp == 1) ? i1 : (comp == 2) ? i2 : i3;
          Ibase_lds[t] = v;
        }
      }
    }
    __syncthreads();
  }

  ((float4*)out)[tid] = ((const float4*)m_lds)[tid];
}

extern "C" void kernel_launch(void* const* d_in, const int* in_sizes, int n_in,
                              void* d_out, int out_size, void* d_ws, size_t ws_size,
                              hipStream_t stream) {
  const float* J = (const float*)d_in[0];
  const float* h = (const float*)d_in[1];
  const float* m0 = (const float*)d_in[2];
  const int* idx = (const int*)d_in[3];
  const float* u = (const float*)d_in[4];
  float* out = (float*)d_out;

  double* thr = (double*)d_ws;                                    // 16384 doubles
  double* I0 = (double*)((char*)d_ws + STEPS * sizeof(double));   // 4096 doubles

  thr_kernel<<<dim3(STEPS / 256), dim3(256), 0, stream>>>(u, thr);
  init_field_kernel<<<dim3(N), dim3(256), 0, stream>>>(J, h, m0, I0);
  pbit_kernel<<<dim3(1), dim3(MBLK), 0, stream>>>(J, m0, idx, thr, I0, out);
}

// Round 2
// 2952.106 us; speedup vs baseline: 1.2444x; 1.2444x over previous
//
#include <hip/hip_runtime.h>
#include <math.h>

#define N 4096
#define STEPS 16384
#define CHUNK 16
#define NCHUNK (STEPS / CHUNK)
#define MBLK 1024

// ---- thresholds: thr[t] = atanh(2*u[t]-1) in double (r computed in fp32 like ref) ----
__global__ __launch_bounds__(256) void thr_kernel(const float* __restrict__ u,
                                                  double* __restrict__ thr) {
  int t = blockIdx.x * 256 + threadIdx.x;
  if (t < STEPS) {
    float r = 2.0f * u[t] - 1.0f;          // exact same fp32 rounding as reference
    double rd = (double)r;
    thr[t] = 0.5 * log((1.0 + rd) / (1.0 - rd));   // r=-1 -> -inf (tie->+1 matches ref)
  }
}

// ---- initial field: I0[row] = sum_k J[row,k]*m0[k] + h[row], fp64 accumulate ----
__global__ __launch_bounds__(256) void init_field_kernel(const float* __restrict__ J,
                                                         const float* __restrict__ h,
                                                         const float* __restrict__ m0,
                                                         double* __restrict__ I) {
  __shared__ double red[256];
  int row = blockIdx.x;
  const float4* Jr = (const float4*)(J + (size_t)row * N);
  const float4* mv = (const float4*)m0;
  double acc = 0.0;
  for (int q = threadIdx.x; q < N / 4; q += 256) {
    float4 a = Jr[q];
    float4 b = mv[q];
    acc += (double)(a.x * b.x) + (double)(a.y * b.y) +
           (double)(a.z * b.z) + (double)(a.w * b.w);
  }
  red[threadIdx.x] = acc;
  __syncthreads();
  for (int s = 128; s > 0; s >>= 1) {
    if (threadIdx.x < s) red[threadIdx.x] += red[threadIdx.x + s];
    __syncthreads();
  }
  if (threadIdx.x == 0) I[row] = red[0] + (double)h[row];
}

// ---- sequential chunk-resolved Glauber chain: 1 workgroup, 1024 threads ----
// Field lives in LDS as fp64 (register write-through by owner threads).
// Wave 0 resolves 16 decisions/chunk via a prefetched 16x16 coupling matrix S
// and publishes {row, delta}; all waves then apply the rank-F update with a
// single branch-free batch of 16 float4 row loads (non-flips -> row 0, x0.0).
__global__ __launch_bounds__(MBLK) void pbit_kernel(const float* __restrict__ J,
                                                    const float* __restrict__ m0,
                                                    const int* __restrict__ idx,
                                                    const double* __restrict__ thr,
                                                    const double* __restrict__ I0,
                                                    float* __restrict__ out) {
  __shared__ __align__(16) double field_lds[N];      // 32 KB master field
  __shared__ __align__(16) float m_lds[N];           // 16 KB spins
  __shared__ __align__(16) float S_lds[CHUNK * CHUNK];
  __shared__ __align__(16) int pubi_lds[CHUNK];      // row to load (0 if no flip)
  __shared__ __align__(16) float pubd_lds[CHUNK];    // delta in {-2,0,+2}

  const int tid = threadIdx.x;

  // owned field elements 4*tid..4*tid+3: fp64 registers + LDS write-through
  double i0, i1, i2, i3;
  {
    const double* ip = I0 + 4 * tid;
    i0 = ip[0]; i1 = ip[1]; i2 = ip[2]; i3 = ip[3];
    *(double2*)(field_lds + 4 * tid + 0) = make_double2(i0, i1);
    *(double2*)(field_lds + 4 * tid + 2) = make_double2(i2, i3);
  }
  ((float4*)m_lds)[tid] = ((const float4*)m0)[tid];

  const int t16 = tid & 15;       // step slot within chunk
  const int gt = tid >> 2;        // S-gather row (tid<64: 0..15)
  const int gq = (tid & 3) * 4;   // S-gather col group
  int myidx = 0, nidx = 0;
  double mythr = 0.0, nthr = 0.0;
  float mym = 0.0f;
  int grow = 0, gc0 = 0, gc1 = 0, gc2 = 0, gc3 = 0;

  if (tid < 64) {
    myidx = idx[t16];
    mythr = thr[t16];
    nidx = idx[CHUNK + t16];
    nthr = thr[CHUNK + t16];
    grow = idx[CHUNK + gt];
    gc0 = idx[CHUNK + gq + 0]; gc1 = idx[CHUNK + gq + 1];
    gc2 = idx[CHUNK + gq + 2]; gc3 = idx[CHUNK + gq + 3];
    // synchronous S gather for chunk 0
    int r0 = idx[gt];
    int c0 = idx[gq + 0], c1 = idx[gq + 1], c2 = idx[gq + 2], c3 = idx[gq + 3];
    const float* Jr = J + (size_t)r0 * N;
    S_lds[gt * CHUNK + gq + 0] = Jr[c0];
    S_lds[gt * CHUNK + gq + 1] = Jr[c1];
    S_lds[gt * CHUNK + gq + 2] = Jr[c2];
    S_lds[gt * CHUNK + gq + 3] = Jr[c3];
  }
  __syncthreads();
  if (tid < 64) mym = m_lds[myidx];

  for (int c = 0; c < NCHUNK; ++c) {
    const int base = c * CHUNK;

    // ---------------- P1: wave 0 resolves the 16 decisions ----------------
    if (tid < 64) {
      // base field for this chunk straight from the LDS-resident field
      double Ival = field_lds[myidx];
      // issue S gather for chunk c+1 (addresses already in regs)
      const float* Jg = J + (size_t)grow * N;
      float g0 = Jg[gc0], g1 = Jg[gc1], g2 = Jg[gc2], g3 = Jg[gc3];
      // issue idx/thr loads for chunk c+2
      int base2 = base + 2 * CHUNK;
      if (base2 >= STEPS) base2 = 0;   // clamp: values unused on final chunks
      int n2idx = idx[base2 + t16];
      double n2thr = thr[base2 + t16];
      int g2row = idx[base2 + gt];
      int g2c0 = idx[base2 + gq + 0], g2c1 = idx[base2 + gq + 1];
      int g2c2 = idx[base2 + gq + 2], g2c3 = idx[base2 + gq + 3];
      // this chunk's S row
      float4 s0 = ((const float4*)S_lds)[t16 * 4 + 0];
      float4 s1 = ((const float4*)S_lds)[t16 * 4 + 1];
      float4 s2 = ((const float4*)S_lds)[t16 * 4 + 2];
      float4 s3 = ((const float4*)S_lds)[t16 * 4 + 3];
      float Srow[CHUNK] = {s0.x, s0.y, s0.z, s0.w, s1.x, s1.y, s1.z, s1.w,
                           s2.x, s2.y, s2.z, s2.w, s3.x, s3.y, s3.z, s3.w};
      float mcur = mym;
      float mydelta = 0.0f, mys = 0.0f;
      bool lastocc = true;
      // serial resolve: lane t decides step t; broadcasts via readlane
#pragma unroll
      for (int tt = 0; tt < CHUNK; ++tt) {
        float s = (Ival >= mythr) ? 1.0f : -1.0f;   // I >= atanh(r) <=> tanh(I) >= r
        float dl = s - mcur;
        float dl_bc = __int_as_float(__builtin_amdgcn_readlane(__float_as_int(dl), tt));
        float s_bc = __int_as_float(__builtin_amdgcn_readlane(__float_as_int(s), tt));
        int i_bc = __builtin_amdgcn_readlane(myidx, tt);
        if (t16 == tt) { mydelta = dl; mys = s; }
        Ival += (double)(Srow[tt] * dl_bc);          // product exact: dl in {-2,0,2}
        if (myidx == i_bc) {                          // in-chunk duplicate index
          if (tt > t16) lastocc = false;
          mcur = s_bc;
        }
      }
      // publish decisions + m updates (last occurrence wins)
      if (tid < CHUNK) {
        pubd_lds[t16] = mydelta;
        pubi_lds[t16] = (mydelta == 0.0f) ? 0 : myidx;   // dummy row 0 when no flip
        if (lastocc) m_lds[myidx] = mys;
      }
      // stage S for chunk c+1 (waits the gather issued above)
      S_lds[gt * CHUNK + gq + 0] = g0;
      S_lds[gt * CHUNK + gq + 1] = g1;
      S_lds[gt * CHUNK + gq + 2] = g2;
      S_lds[gt * CHUNK + gq + 3] = g3;
      // m gather for chunk c+1 (after this chunk's m writes; same wave, in-order)
      mym = m_lds[nidx];
      // shift pipeline registers
      myidx = nidx; mythr = nthr;
      nidx = n2idx; nthr = n2thr;
      grow = g2row; gc0 = g2c0; gc1 = g2c1; gc2 = g2c2; gc3 = g2c3;
    }
    __syncthreads();

    // ---------------- P2: all threads apply rank-F update ----------------
    {
      int4 pi0 = ((const int4*)pubi_lds)[0];
      int4 pi1 = ((const int4*)pubi_lds)[1];
      int4 pi2 = ((const int4*)pubi_lds)[2];
      int4 pi3 = ((const int4*)pubi_lds)[3];
      float4 pd0 = ((const float4*)pubd_lds)[0];
      float4 pd1 = ((const float4*)pubd_lds)[1];
      float4 pd2 = ((const float4*)pubd_lds)[2];
      float4 pd3 = ((const float4*)pubd_lds)[3];
      int ab = __float_as_int(pd0.x) | __float_as_int(pd0.y) |
               __float_as_int(pd0.z) | __float_as_int(pd0.w) |
               __float_as_int(pd1.x) | __float_as_int(pd1.y) |
               __float_as_int(pd1.z) | __float_as_int(pd1.w) |
               __float_as_int(pd2.x) | __float_as_int(pd2.y) |
               __float_as_int(pd2.z) | __float_as_int(pd2.w) |
               __float_as_int(pd3.x) | __float_as_int(pd3.y) |
               __float_as_int(pd3.z) | __float_as_int(pd3.w);
      if (ab != 0) {                       // uniform: skip chunks with zero flips
        const float* Jb = J + 4 * tid;
        int rows[CHUNK] = {pi0.x, pi0.y, pi0.z, pi0.w, pi1.x, pi1.y, pi1.z, pi1.w,
                           pi2.x, pi2.y, pi2.z, pi2.w, pi3.x, pi3.y, pi3.z, pi3.w};
        float dv[CHUNK] = {pd0.x, pd0.y, pd0.z, pd0.w, pd1.x, pd1.y, pd1.z, pd1.w,
                           pd2.x, pd2.y, pd2.z, pd2.w, pd3.x, pd3.y, pd3.z, pd3.w};
        float4 rv[CHUNK];
        // branch-free: all 16 loads issue back-to-back (one latency exposure);
        // non-flips load row 0 (L1-resident) and multiply by exactly 0.0
#pragma unroll
        for (int t = 0; t < CHUNK; ++t)
          rv[t] = *(const float4*)(Jb + ((size_t)rows[t] * N));
        float a0 = 0.f, a1 = 0.f, a2 = 0.f, a3 = 0.f;
#pragma unroll
        for (int t = 0; t < CHUNK; ++t) {
          a0 += rv[t].x * dv[t]; a1 += rv[t].y * dv[t];
          a2 += rv[t].z * dv[t]; a3 += rv[t].w * dv[t];
        }
        // chunk-local exact fp32 partials -> fp64 master, write-through to LDS
        i0 += (double)a0; i1 += (double)a1; i2 += (double)a2; i3 += (double)a3;
        *(double2*)(field_lds + 4 * tid + 0) = make_double2(i0, i1);
        *(double2*)(field_lds + 4 * tid + 2) = make_double2(i2, i3);
      }
    }
    __syncthreads();
  }

  ((float4*)out)[tid] = ((const float4*)m_lds)[tid];
}

extern "C" void kernel_launch(void* const* d_in, const int* in_sizes, int n_in,
                              void* d_out, int out_size, void* d_ws, size_t ws_size,
                              hipStream_t stream) {
  const float* J = (const float*)d_in[0];
  const float* h = (const float*)d_in[1];
  const float* m0 = (const float*)d_in[2];
  const int* idx = (const int*)d_in[3];
  const float* u = (const float*)d_in[4];
  float* out = (float*)d_out;

  double* thr = (double*)d_ws;                                    // 16384 doubles
  double* I0 = (double*)((char*)d_ws + STEPS * sizeof(double));   // 4096 doubles

  thr_kernel<<<dim3(STEPS / 256), dim3(256), 0, stream>>>(u, thr);
  init_field_kernel<<<dim3(N), dim3(256), 0, stream>>>(J, h, m0, I0);
  pbit_kernel<<<dim3(1), dim3(MBLK), 0, stream>>>(J, m0, idx, thr, I0, out);
}